// Round 6
// baseline (300.982 us; speedup 1.0000x reference)
//
#include <hip/hip_runtime.h>

// Problem constants (GATConv_17635135717523)
// N=50000 nodes, E=800000 edges, IN=256, H=8, O=32, H*O=256
#define N_NODES 50000
#define N_EDGES 800000
#define NPAD    50176   // 196*256

typedef __bf16 bf16x8 __attribute__((ext_vector_type(8)));
typedef float  fx4    __attribute__((ext_vector_type(4)));
typedef unsigned short us4 __attribute__((ext_vector_type(4)));
typedef unsigned short us8 __attribute__((ext_vector_type(8)));

__device__ __forceinline__ float b2f(unsigned short u) {
    return __uint_as_float(((unsigned)u) << 16);
}
__device__ __forceinline__ unsigned short f2b(float f) {
    unsigned x = __float_as_uint(f);
    return (unsigned short)((x + 0x7FFFu + ((x >> 16) & 1u)) >> 16);
}

// ------------------------------------------------------- W prep + cnt zero
// blocks 0..255: Wt[n][k] = bf16(W[k][n])  (n-major, k contiguous)
// blocks 256..271: M2t[j][k] hi/lo, j<8 -> el head j, j>=8 -> er head j-8
// blocks 272..467: zero cnt (replaces hipMemsetAsync; stream order covers gemm)
__global__ __launch_bounds__(256) void prep_w(
    const float* __restrict__ W,
    const float* __restrict__ attn_l, const float* __restrict__ attn_r,
    unsigned short* __restrict__ Wt,
    unsigned short* __restrict__ M2t_hi, unsigned short* __restrict__ M2t_lo,
    int* __restrict__ cnt) {
    int b = blockIdx.x, k = threadIdx.x;
    if (b < 256) {
        Wt[b * 256 + k] = f2b(W[k * 256 + b]);
    } else if (b < 272) {
        int j = b - 256;
        const float* av = (j < 8) ? (attn_l + j * 32) : (attn_r + (j - 8) * 32);
        int c0 = (j & 7) * 32;
        float s = 0.f;
#pragma unroll
        for (int o = 0; o < 32; ++o) s += W[k * 256 + c0 + o] * av[o];
        unsigned short h = f2b(s);
        M2t_hi[j * 256 + k] = h;
        M2t_lo[j * 256 + k] = f2b(s - b2f(h));
    } else {
        cnt[(b - 272) * 256 + k] = 0;
    }
}

// ------------------------------------------------------- fused GEMM + count_deg
// ft = bf16(feat @ W); el/er = feat @ M2 (fp32 out, M2 in hi+lo bf16).
// Block: 64 rows x 256 cols, 4 waves (wave w owns cols [w*64,w*64+64)).
// feat fp32 staged -> bf16 LDS tile [64][40] (pad 32->40).
// Tail: each thread also counts 4 edges' dst degrees (independent work;
// only the NEXT dispatch needs the atomics complete).
__global__ __launch_bounds__(256) void gemm_ft(
    const float* __restrict__ feat,
    const unsigned short* __restrict__ Wt,
    const unsigned short* __restrict__ M2t_hi,
    const unsigned short* __restrict__ M2t_lo,
    unsigned short* __restrict__ ft,
    float* __restrict__ el, float* __restrict__ er,
    const int* __restrict__ dst, int* __restrict__ cnt) {
    __shared__ unsigned short Alds[64 * 40];
    const int tid  = threadIdx.x;
    const int lane = tid & 63;
    const int wid  = tid >> 6;
    const int quad = lane >> 4, l15 = lane & 15;
    const int mbase = blockIdx.x * 64;
    const int nbase = wid * 64;

    fx4 acc[4][4];
    fx4 acce[4];
#pragma unroll
    for (int i = 0; i < 4; ++i) {
        acce[i] = (fx4)0.0f;
#pragma unroll
        for (int j = 0; j < 4; ++j) acc[i][j] = (fx4)0.0f;
    }

    // staging role: thread -> (row, 8-elem k segment)
    const int srow  = tid >> 2;
    const int skseg = (tid & 3) * 8;
    int grow = mbase + srow;
    grow = grow < N_NODES ? grow : N_NODES - 1;
    const float* sp = feat + (size_t)grow * 256 + skseg;
    unsigned short* sdst = &Alds[srow * 40 + skseg];

    for (int k0 = 0; k0 < 256; k0 += 32) {
        __syncthreads();
        float4 f0 = *reinterpret_cast<const float4*>(sp + k0);
        float4 f1 = *reinterpret_cast<const float4*>(sp + k0 + 4);
        us8 pk;
        pk[0] = f2b(f0.x); pk[1] = f2b(f0.y); pk[2] = f2b(f0.z); pk[3] = f2b(f0.w);
        pk[4] = f2b(f1.x); pk[5] = f2b(f1.y); pk[6] = f2b(f1.z); pk[7] = f2b(f1.w);
        *reinterpret_cast<us8*>(sdst) = pk;
        __syncthreads();

        const int krow = k0 + quad * 8;
        bf16x8 a[4], b[4];
#pragma unroll
        for (int mt = 0; mt < 4; ++mt)
            a[mt] = *reinterpret_cast<const bf16x8*>(&Alds[(mt * 16 + l15) * 40 + quad * 8]);
#pragma unroll
        for (int nt = 0; nt < 4; ++nt)
            b[nt] = *reinterpret_cast<const bf16x8*>(Wt + (nbase + nt * 16 + l15) * 256 + krow);
#pragma unroll
        for (int mt = 0; mt < 4; ++mt)
#pragma unroll
            for (int nt = 0; nt < 4; ++nt)
                acc[mt][nt] = __builtin_amdgcn_mfma_f32_16x16x32_bf16(
                    a[mt], b[nt], acc[mt][nt], 0, 0, 0);
        if (wid == 0) {
            bf16x8 bh = *reinterpret_cast<const bf16x8*>(M2t_hi + l15 * 256 + krow);
            bf16x8 bl = *reinterpret_cast<const bf16x8*>(M2t_lo + l15 * 256 + krow);
#pragma unroll
            for (int mt = 0; mt < 4; ++mt) {
                acce[mt] = __builtin_amdgcn_mfma_f32_16x16x32_bf16(a[mt], bh, acce[mt], 0, 0, 0);
                acce[mt] = __builtin_amdgcn_mfma_f32_16x16x32_bf16(a[mt], bl, acce[mt], 0, 0, 0);
            }
        }
    }

    // C/D layout: col = lane&15, row = (lane>>4)*4 + reg  [verified m89/m91]
#pragma unroll
    for (int mt = 0; mt < 4; ++mt) {
#pragma unroll
        for (int r = 0; r < 4; ++r) {
            int row = mbase + mt * 16 + quad * 4 + r;
            if (row < N_NODES) {
#pragma unroll
                for (int nt = 0; nt < 4; ++nt)
                    ft[(size_t)row * 256 + nbase + nt * 16 + l15] = f2b(acc[mt][nt][r]);
            }
        }
    }
    if (wid == 0) {
#pragma unroll
        for (int mt = 0; mt < 4; ++mt) {
#pragma unroll
            for (int r = 0; r < 4; ++r) {
                int row = mbase + mt * 16 + quad * 4 + r;
                if (row < N_NODES) {
                    float v = acce[mt][r];
                    if (l15 < 8) el[row * 8 + l15] = v;
                    else         er[row * 8 + (l15 - 8)] = v;
                }
            }
        }
    }

    // fused count_deg tail: 782*256 = 200192 threads >= 200000 int4s
    int t = blockIdx.x * 256 + tid;
    if (t < N_EDGES / 4) {
        int4 d = reinterpret_cast<const int4*>(dst)[t];
        atomicAdd(&cnt[d.x], 1);
        atomicAdd(&cnt[d.y], 1);
        atomicAdd(&cnt[d.z], 1);
        atomicAdd(&cnt[d.w], 1);
    }
}

// ------------------------------------------------------- single-kernel scan
// 1024 threads, one block. Coalesced global reads staged to LDS as uchar
// (deg max ~50 for Poisson(16); P(deg>=256) ~ 1e-469 -> uchar safe).
// Thread t owns contiguous chunk [t*49, t*49+49); Hillis-Steele over partials.
__global__ __launch_bounds__(1024) void scan_all(
    const int* __restrict__ cnt, int* __restrict__ off, int* __restrict__ cursor) {
    __shared__ unsigned char c8[NPAD];   // 49 KB
    __shared__ int ps[1024];
    int t = threadIdx.x;
    for (int i = t; i < NPAD / 4; i += 1024) {
        int4 v = reinterpret_cast<const int4*>(cnt)[i];
        unsigned pack = (unsigned)v.x | ((unsigned)v.y << 8) |
                        ((unsigned)v.z << 16) | ((unsigned)v.w << 24);
        reinterpret_cast<unsigned*>(c8)[i] = pack;
    }
    __syncthreads();
    int base = t * 49;
    int s = 0;
#pragma unroll
    for (int i = 0; i < 49; ++i) s += c8[base + i];
    ps[t] = s;
    __syncthreads();
    for (int d = 1; d < 1024; d <<= 1) {
        int add = (t >= d) ? ps[t - d] : 0;
        __syncthreads();
        ps[t] += add;
        __syncthreads();
    }
    int run = ps[t] - s;   // exclusive prefix of this thread's chunk
#pragma unroll
    for (int i = 0; i < 49; ++i) {
        off[base + i] = run;
        cursor[base + i] = run;
        run += c8[base + i];
    }
}

// ------------------------------------------------------- bucket edges
__global__ __launch_bounds__(256) void bucket_edges(
    const int* __restrict__ src, const int* __restrict__ dst,
    int* __restrict__ cursor, int* __restrict__ inedge_src) {
    int t = blockIdx.x * 256 + threadIdx.x;
    if (t < N_EDGES / 4) {
        int4 s = reinterpret_cast<const int4*>(src)[t];
        int4 d = reinterpret_cast<const int4*>(dst)[t];
        inedge_src[atomicAdd(&cursor[d.x], 1)] = s.x;
        inedge_src[atomicAdd(&cursor[d.y], 1)] = s.y;
        inedge_src[atomicAdd(&cursor[d.z], 1)] = s.z;
        inedge_src[atomicAdd(&cursor[d.w], 1)] = s.w;
    }
}

// ------------------------------------------------------- aggregation v4
// One wave per dst node, single edge pass, HALF-WAVE per edge:
// 32 lanes cover a 512B ft row at 16B/lane (us8); the two halves process
// edge pairs (j, j+1) concurrently; cross-half combine via shfl_xor(32).
// Softmax denom accumulated inline (no max-subtraction; |logit| ~ O(1)).
__global__ __launch_bounds__(256) void aggregate(
    const unsigned short* __restrict__ ft,
    const float* __restrict__ el, const float* __restrict__ er,
    const int* __restrict__ off, const int* __restrict__ cnt,
    const int* __restrict__ inedge_src,
    const float* __restrict__ bias,
    float* __restrict__ out) {
    int wid = threadIdx.x >> 6, lane = threadIdx.x & 63;
    int v = blockIdx.x * 4 + wid;          // grid exact: v < N always
    int start = off[v], deg = cnt[v];
    int half = lane >> 5, l = lane & 31;
    int h = l >> 2;                         // head of elems [l*8, l*8+8)
    float erv = er[v * 8 + h];
    const int* ip = inedge_src + start;
    const us8* ft8 = reinterpret_cast<const us8*>(ft);

    float a[8] = {0.f, 0.f, 0.f, 0.f, 0.f, 0.f, 0.f, 0.f};
    float s = 0.f;
    int j = 0;
    for (; j + 8 <= deg; j += 8) {          // 4 pairs = 8 edges per iter
        int u[4];
#pragma unroll
        for (int t = 0; t < 4; ++t) u[t] = ip[j + 2 * t + half];
        us8 f[4];
#pragma unroll
        for (int t = 0; t < 4; ++t) f[t] = ft8[(size_t)u[t] * 32 + l];
#pragma unroll
        for (int t = 0; t < 4; ++t) {
            float x = el[u[t] * 8 + h] + erv;
            x = x > 0.f ? x : 0.2f * x;
            float w = __expf(x);
            s += w;
#pragma unroll
            for (int i = 0; i < 8; ++i) a[i] += w * b2f(f[t][i]);
        }
    }
    for (; j + 2 <= deg; j += 2) {          // pair tail
        int u = ip[j + half];
        us8 f = ft8[(size_t)u * 32 + l];
        float x = el[u * 8 + h] + erv;
        x = x > 0.f ? x : 0.2f * x;
        float w = __expf(x);
        s += w;
#pragma unroll
        for (int i = 0; i < 8; ++i) a[i] += w * b2f(f[i]);
    }
    if (j < deg && half == 0) {             // odd edge: half 0 only
        int u = ip[j];
        us8 f = ft8[(size_t)u * 32 + l];
        float x = el[u * 8 + h] + erv;
        x = x > 0.f ? x : 0.2f * x;
        float w = __expf(x);
        s += w;
#pragma unroll
        for (int i = 0; i < 8; ++i) a[i] += w * b2f(f[i]);
    }
    // combine halves (both halves end with full sums)
#pragma unroll
    for (int i = 0; i < 8; ++i) a[i] += __shfl_xor(a[i], 32);
    s += __shfl_xor(s, 32);
    float inv = deg > 0 ? 1.0f / s : 0.f;

    // write: lane stores 4 floats at float4-index l*2+half of the row
    int fi = l * 2 + half;
    float4 bb = reinterpret_cast<const float4*>(bias)[fi];
    int base = half * 4;
    float4 o;
    o.x = a[base + 0] * inv + bb.x;
    o.y = a[base + 1] * inv + bb.y;
    o.z = a[base + 2] * inv + bb.z;
    o.w = a[base + 3] * inv + bb.w;
    reinterpret_cast<float4*>(out)[(size_t)v * 64 + fi] = o;
}

// ------------------------------------------------------- launch (5 dispatches)
extern "C" void kernel_launch(void* const* d_in, const int* in_sizes, int n_in,
                              void* d_out, int out_size, void* d_ws, size_t ws_size,
                              hipStream_t stream) {
    const float* feat   = (const float*)d_in[0];
    const float* W      = (const float*)d_in[1];
    const float* attn_l = (const float*)d_in[2];
    const float* attn_r = (const float*)d_in[3];
    const float* bias   = (const float*)d_in[4];
    const int* src = (const int*)d_in[5];
    const int* dst = (const int*)d_in[6];
    float* out = (float*)d_out;

    char* ws = (char*)d_ws;
    // workspace layout (16B aligned), ~32.8 MB total
    unsigned short* Wt     = (unsigned short*)(ws + 0);          //    131,072
    unsigned short* M2t_hi = (unsigned short*)(ws + 131072);     //      8,192
    unsigned short* M2t_lo = (unsigned short*)(ws + 139264);     //      8,192
    unsigned short* ft     = (unsigned short*)(ws + 147456);     // 25,600,000
    float* el              = (float*)(ws + 25747456);            //  1,600,000
    float* er              = (float*)(ws + 27347456);            //  1,600,000
    int* cnt               = (int*)(ws + 28947456);              //    200,704
    int* off               = (int*)(ws + 29148160);              //    200,704
    int* cursor            = (int*)(ws + 29348864);              //    200,704
    int* inedge_src        = (int*)(ws + 29549568);              //  3,200,000

    prep_w<<<468, 256, 0, stream>>>(W, attn_l, attn_r, Wt, M2t_hi, M2t_lo, cnt);
    gemm_ft<<<782, 256, 0, stream>>>(feat, Wt, M2t_hi, M2t_lo, ft, el, er, dst, cnt);
    scan_all<<<1, 1024, 0, stream>>>(cnt, off, cursor);
    bucket_edges<<<782, 256, 0, stream>>>(src, dst, cursor, inedge_src);
    aggregate<<<12500, 256, 0, stream>>>(ft, el, er, off, cnt, inedge_src, bias, out);
}

// Round 7
// 285.786 us; speedup vs baseline: 1.0532x; 1.0532x over previous
//
#include <hip/hip_runtime.h>

// Problem constants (GATConv_17635135717523)
// N=50000 nodes, E=800000 edges, IN=256, H=8, O=32, H*O=256
#define N_NODES 50000
#define N_EDGES 800000
#define NPAD    50176   // 196*256

typedef __bf16 bf16x8 __attribute__((ext_vector_type(8)));
typedef float  fx4    __attribute__((ext_vector_type(4)));
typedef unsigned short us4 __attribute__((ext_vector_type(4)));
typedef unsigned short us8 __attribute__((ext_vector_type(8)));

__device__ __forceinline__ float b2f(unsigned short u) {
    return __uint_as_float(((unsigned)u) << 16);
}
__device__ __forceinline__ unsigned short f2b(float f) {
    unsigned x = __float_as_uint(f);
    return (unsigned short)((x + 0x7FFFu + ((x >> 16) & 1u)) >> 16);
}

// ------------------------------------------------------- W prep + cnt zero
// blocks 0..255: Wt[n][k] = bf16(W[k][n])  (n-major, k contiguous)
// blocks 256..271: M2t[j][k] hi/lo, j<8 -> el head j, j>=8 -> er head j-8
// blocks 272..467: zero cnt (stream order covers gemm's count_deg tail)
__global__ __launch_bounds__(256) void prep_w(
    const float* __restrict__ W,
    const float* __restrict__ attn_l, const float* __restrict__ attn_r,
    unsigned short* __restrict__ Wt,
    unsigned short* __restrict__ M2t_hi, unsigned short* __restrict__ M2t_lo,
    int* __restrict__ cnt) {
    int b = blockIdx.x, k = threadIdx.x;
    if (b < 256) {
        Wt[b * 256 + k] = f2b(W[k * 256 + b]);
    } else if (b < 272) {
        int j = b - 256;
        const float* av = (j < 8) ? (attn_l + j * 32) : (attn_r + (j - 8) * 32);
        int c0 = (j & 7) * 32;
        float s = 0.f;
#pragma unroll
        for (int o = 0; o < 32; ++o) s += W[k * 256 + c0 + o] * av[o];
        unsigned short h = f2b(s);
        M2t_hi[j * 256 + k] = h;
        M2t_lo[j * 256 + k] = f2b(s - b2f(h));
    } else {
        cnt[(b - 272) * 256 + k] = 0;
    }
}

// ------------------------------------------------------- fused GEMM + count_deg
// ft = bf16(feat @ W); el/er = feat @ M2 (fp32 out, M2 in hi+lo bf16).
// Block: 64 rows x 256 cols, 4 waves (wave w owns cols [w*64,w*64+64)).
// v2 structure: full 64x256 feat tile staged ONCE (16 independent float4
// loads/thread -> bf16 LDS, stride 264, chunk-pair swizzle = conflict-free),
// then ONE barrier, then 8 barrier-free K-iterations from LDS.
// Epilogue: acc bounced via per-wave LDS to emit 16B us8 ft stores.
__global__ __launch_bounds__(256) void gemm_ft(
    const float* __restrict__ feat,
    const unsigned short* __restrict__ Wt,
    const unsigned short* __restrict__ M2t_hi,
    const unsigned short* __restrict__ M2t_lo,
    unsigned short* __restrict__ ft,
    float* __restrict__ el, float* __restrict__ er,
    const int* __restrict__ dst, int* __restrict__ cnt) {
    __shared__ unsigned short Alds[64 * 264];        // 33792 B
    __shared__ unsigned short Bounce[4][16 * 64];    // 8192 B, per-wave
    const int tid  = threadIdx.x;
    const int lane = tid & 63;
    const int wid  = tid >> 6;
    const int quad = lane >> 4, l15 = lane & 15;
    const int mbase = blockIdx.x * 64;
    const int nbase = wid * 64;

    fx4 acc[4][4];
    fx4 acce[4];
#pragma unroll
    for (int i = 0; i < 4; ++i) {
        acce[i] = (fx4)0.0f;
#pragma unroll
        for (int j = 0; j < 4; ++j) acc[i][j] = (fx4)0.0f;
    }

    // ---- stage whole tile: thread (srow, squart) covers chunk pairs
    // c8 = ii*8 + squart*2 (chunks of 8 floats); 4-thread cluster = 256B runs.
    {
        const int srow = tid >> 2, squart = tid & 3;
        int grow = mbase + srow;
        grow = grow < N_NODES ? grow : N_NODES - 1;
        const float* sp = feat + (size_t)grow * 256;
        unsigned short* sd = &Alds[srow * 264];
#pragma unroll
        for (int ii = 0; ii < 4; ++ii) {
            int c8 = ii * 8 + squart * 2;
            float4 f0 = *reinterpret_cast<const float4*>(sp + c8 * 8);
            float4 f1 = *reinterpret_cast<const float4*>(sp + c8 * 8 + 4);
            float4 f2 = *reinterpret_cast<const float4*>(sp + c8 * 8 + 8);
            float4 f3 = *reinterpret_cast<const float4*>(sp + c8 * 8 + 12);
            us8 p0, p1;
            p0[0] = f2b(f0.x); p0[1] = f2b(f0.y); p0[2] = f2b(f0.z); p0[3] = f2b(f0.w);
            p0[4] = f2b(f1.x); p0[5] = f2b(f1.y); p0[6] = f2b(f1.z); p0[7] = f2b(f1.w);
            p1[0] = f2b(f2.x); p1[1] = f2b(f2.y); p1[2] = f2b(f2.z); p1[3] = f2b(f2.w);
            p1[4] = f2b(f3.x); p1[5] = f2b(f3.y); p1[6] = f2b(f3.z); p1[7] = f2b(f3.w);
            *reinterpret_cast<us8*>(sd + c8 * 8) = p0;
            *reinterpret_cast<us8*>(sd + c8 * 8 + 8) = p1;
        }
    }
    __syncthreads();   // the ONLY barrier

    // ---- K loop, barrier-free
    for (int k0 = 0; k0 < 256; k0 += 32) {
        const int krow = k0 + quad * 8;
        bf16x8 a[4], b[4];
#pragma unroll
        for (int mt = 0; mt < 4; ++mt)
            a[mt] = *reinterpret_cast<const bf16x8*>(&Alds[(mt * 16 + l15) * 264 + krow]);
#pragma unroll
        for (int nt = 0; nt < 4; ++nt)
            b[nt] = *reinterpret_cast<const bf16x8*>(Wt + (nbase + nt * 16 + l15) * 256 + krow);
#pragma unroll
        for (int mt = 0; mt < 4; ++mt)
#pragma unroll
            for (int nt = 0; nt < 4; ++nt)
                acc[mt][nt] = __builtin_amdgcn_mfma_f32_16x16x32_bf16(
                    a[mt], b[nt], acc[mt][nt], 0, 0, 0);
        if (wid == 0) {
            bf16x8 bh = *reinterpret_cast<const bf16x8*>(M2t_hi + l15 * 256 + krow);
            bf16x8 bl = *reinterpret_cast<const bf16x8*>(M2t_lo + l15 * 256 + krow);
#pragma unroll
            for (int mt = 0; mt < 4; ++mt) {
                acce[mt] = __builtin_amdgcn_mfma_f32_16x16x32_bf16(a[mt], bh, acce[mt], 0, 0, 0);
                acce[mt] = __builtin_amdgcn_mfma_f32_16x16x32_bf16(a[mt], bl, acce[mt], 0, 0, 0);
            }
        }
    }

    // ---- packed epilogue: per-wave LDS bounce -> us8 (16B) ft stores
    // C/D layout: col = lane&15, row = (lane>>4)*4 + reg  [verified m89/m91]
    unsigned short* bw = Bounce[wid];
#pragma unroll
    for (int mt = 0; mt < 4; ++mt) {
#pragma unroll
        for (int r = 0; r < 4; ++r) {
            int rl = quad * 4 + r;
#pragma unroll
            for (int nt = 0; nt < 4; ++nt)
                bw[rl * 64 + nt * 16 + l15] = f2b(acc[mt][nt][r]);
        }
        // wave-internal ds ordering; compiler inserts lgkmcnt wait
#pragma unroll
        for (int it = 0; it < 2; ++it) {
            int rl = (lane >> 3) + it * 8;
            int c8 = lane & 7;
            us8 v = *reinterpret_cast<const us8*>(&bw[rl * 64 + c8 * 8]);
            int grow = mbase + mt * 16 + rl;
            if (grow < N_NODES)
                *reinterpret_cast<us8*>(ft + (size_t)grow * 256 + nbase + c8 * 8) = v;
        }
    }
    if (wid == 0) {
#pragma unroll
        for (int mt = 0; mt < 4; ++mt) {
#pragma unroll
            for (int r = 0; r < 4; ++r) {
                int row = mbase + mt * 16 + quad * 4 + r;
                if (row < N_NODES) {
                    float v = acce[mt][r];
                    if (l15 < 8) el[row * 8 + l15] = v;
                    else         er[row * 8 + (l15 - 8)] = v;
                }
            }
        }
    }

    // fused count_deg tail: 782*256 = 200192 threads >= 200000 int4s
    int t = blockIdx.x * 256 + tid;
    if (t < N_EDGES / 4) {
        int4 d = reinterpret_cast<const int4*>(dst)[t];
        atomicAdd(&cnt[d.x], 1);
        atomicAdd(&cnt[d.y], 1);
        atomicAdd(&cnt[d.z], 1);
        atomicAdd(&cnt[d.w], 1);
    }
}

// ------------------------------------------------------- single-kernel scan
// 1024 threads, one block. Coalesced global reads staged to LDS as uchar
// (deg max ~50 for Poisson(16); P(deg>=256) ~ 1e-469 -> uchar safe).
__global__ __launch_bounds__(1024) void scan_all(
    const int* __restrict__ cnt, int* __restrict__ off, int* __restrict__ cursor) {
    __shared__ unsigned char c8[NPAD];   // 49 KB
    __shared__ int ps[1024];
    int t = threadIdx.x;
    for (int i = t; i < NPAD / 4; i += 1024) {
        int4 v = reinterpret_cast<const int4*>(cnt)[i];
        unsigned pack = (unsigned)v.x | ((unsigned)v.y << 8) |
                        ((unsigned)v.z << 16) | ((unsigned)v.w << 24);
        reinterpret_cast<unsigned*>(c8)[i] = pack;
    }
    __syncthreads();
    int base = t * 49;
    int s = 0;
#pragma unroll
    for (int i = 0; i < 49; ++i) s += c8[base + i];
    ps[t] = s;
    __syncthreads();
    for (int d = 1; d < 1024; d <<= 1) {
        int add = (t >= d) ? ps[t - d] : 0;
        __syncthreads();
        ps[t] += add;
        __syncthreads();
    }
    int run = ps[t] - s;   // exclusive prefix of this thread's chunk
#pragma unroll
    for (int i = 0; i < 49; ++i) {
        off[base + i] = run;
        cursor[base + i] = run;
        run += c8[base + i];
    }
}

// ------------------------------------------------------- bucket edges
__global__ __launch_bounds__(256) void bucket_edges(
    const int* __restrict__ src, const int* __restrict__ dst,
    int* __restrict__ cursor, int* __restrict__ inedge_src) {
    int t = blockIdx.x * 256 + threadIdx.x;
    if (t < N_EDGES / 4) {
        int4 s = reinterpret_cast<const int4*>(src)[t];
        int4 d = reinterpret_cast<const int4*>(dst)[t];
        inedge_src[atomicAdd(&cursor[d.x], 1)] = s.x;
        inedge_src[atomicAdd(&cursor[d.y], 1)] = s.y;
        inedge_src[atomicAdd(&cursor[d.z], 1)] = s.z;
        inedge_src[atomicAdd(&cursor[d.w], 1)] = s.w;
    }
}

// ------------------------------------------------------- aggregation v4
// One wave per dst node, single edge pass, HALF-WAVE per edge:
// 32 lanes cover a 512B ft row at 16B/lane (us8); the two halves process
// edge pairs (j, j+1) concurrently; cross-half combine via shfl_xor(32).
// Softmax denom accumulated inline (no max-subtraction; |logit| ~ O(1)).
__global__ __launch_bounds__(256) void aggregate(
    const unsigned short* __restrict__ ft,
    const float* __restrict__ el, const float* __restrict__ er,
    const int* __restrict__ off, const int* __restrict__ cnt,
    const int* __restrict__ inedge_src,
    const float* __restrict__ bias,
    float* __restrict__ out) {
    int wid = threadIdx.x >> 6, lane = threadIdx.x & 63;
    int v = blockIdx.x * 4 + wid;          // grid exact: v < N always
    int start = off[v], deg = cnt[v];
    int half = lane >> 5, l = lane & 31;
    int h = l >> 2;                         // head of elems [l*8, l*8+8)
    float erv = er[v * 8 + h];
    const int* ip = inedge_src + start;
    const us8* ft8 = reinterpret_cast<const us8*>(ft);

    float a[8] = {0.f, 0.f, 0.f, 0.f, 0.f, 0.f, 0.f, 0.f};
    float s = 0.f;
    int j = 0;
    for (; j + 8 <= deg; j += 8) {          // 4 pairs = 8 edges per iter
        int u[4];
#pragma unroll
        for (int t = 0; t < 4; ++t) u[t] = ip[j + 2 * t + half];
        us8 f[4];
#pragma unroll
        for (int t = 0; t < 4; ++t) f[t] = ft8[(size_t)u[t] * 32 + l];
#pragma unroll
        for (int t = 0; t < 4; ++t) {
            float x = el[u[t] * 8 + h] + erv;
            x = x > 0.f ? x : 0.2f * x;
            float w = __expf(x);
            s += w;
#pragma unroll
            for (int i = 0; i < 8; ++i) a[i] += w * b2f(f[t][i]);
        }
    }
    for (; j + 2 <= deg; j += 2) {          // pair tail
        int u = ip[j + half];
        us8 f = ft8[(size_t)u * 32 + l];
        float x = el[u * 8 + h] + erv;
        x = x > 0.f ? x : 0.2f * x;
        float w = __expf(x);
        s += w;
#pragma unroll
        for (int i = 0; i < 8; ++i) a[i] += w * b2f(f[i]);
    }
    if (j < deg && half == 0) {             // odd edge: half 0 only
        int u = ip[j];
        us8 f = ft8[(size_t)u * 32 + l];
        float x = el[u * 8 + h] + erv;
        x = x > 0.f ? x : 0.2f * x;
        float w = __expf(x);
        s += w;
#pragma unroll
        for (int i = 0; i < 8; ++i) a[i] += w * b2f(f[i]);
    }
    // combine halves (both halves end with full sums)
#pragma unroll
    for (int i = 0; i < 8; ++i) a[i] += __shfl_xor(a[i], 32);
    s += __shfl_xor(s, 32);
    float inv = deg > 0 ? 1.0f / s : 0.f;

    // write: lane stores 4 floats at float4-index l*2+half of the row
    int fi = l * 2 + half;
    float4 bb = reinterpret_cast<const float4*>(bias)[fi];
    int base = half * 4;
    float4 o;
    o.x = a[base + 0] * inv + bb.x;
    o.y = a[base + 1] * inv + bb.y;
    o.z = a[base + 2] * inv + bb.z;
    o.w = a[base + 3] * inv + bb.w;
    reinterpret_cast<float4*>(out)[(size_t)v * 64 + fi] = o;
}

// ------------------------------------------------------- launch (5 dispatches)
extern "C" void kernel_launch(void* const* d_in, const int* in_sizes, int n_in,
                              void* d_out, int out_size, void* d_ws, size_t ws_size,
                              hipStream_t stream) {
    const float* feat   = (const float*)d_in[0];
    const float* W      = (const float*)d_in[1];
    const float* attn_l = (const float*)d_in[2];
    const float* attn_r = (const float*)d_in[3];
    const float* bias   = (const float*)d_in[4];
    const int* src = (const int*)d_in[5];
    const int* dst = (const int*)d_in[6];
    float* out = (float*)d_out;

    char* ws = (char*)d_ws;
    // workspace layout (16B aligned), ~32.8 MB total
    unsigned short* Wt     = (unsigned short*)(ws + 0);          //    131,072
    unsigned short* M2t_hi = (unsigned short*)(ws + 131072);     //      8,192
    unsigned short* M2t_lo = (unsigned short*)(ws + 139264);     //      8,192
    unsigned short* ft     = (unsigned short*)(ws + 147456);     // 25,600,000
    float* el              = (float*)(ws + 25747456);            //  1,600,000
    float* er              = (float*)(ws + 27347456);            //  1,600,000
    int* cnt               = (int*)(ws + 28947456);              //    200,704
    int* off               = (int*)(ws + 29148160);              //    200,704
    int* cursor            = (int*)(ws + 29348864);              //    200,704
    int* inedge_src        = (int*)(ws + 29549568);              //  3,200,000

    prep_w<<<468, 256, 0, stream>>>(W, attn_l, attn_r, Wt, M2t_hi, M2t_lo, cnt);
    gemm_ft<<<782, 256, 0, stream>>>(feat, Wt, M2t_hi, M2t_lo, ft, el, er, dst, cnt);
    scan_all<<<1, 1024, 0, stream>>>(cnt, off, cursor);
    bucket_edges<<<782, 256, 0, stream>>>(src, dst, cursor, inedge_src);
    aggregate<<<12500, 256, 0, stream>>>(ft, el, er, off, cnt, inedge_src, bias, out);
}